// Round 2
// baseline (1129.803 us; speedup 1.0000x reference)
//
#include <hip/hip_runtime.h>

typedef _Float16 f16;
typedef __attribute__((ext_vector_type(8))) _Float16 half8;
typedef __attribute__((ext_vector_type(4))) float f32x4;

struct f16x4 { f16 a, b, c, d; };

__device__ __forceinline__ void glds16(const f16* g, f16* l) {
  __builtin_amdgcn_global_load_lds(
      (const __attribute__((address_space(1))) void*)g,
      (__attribute__((address_space(3))) void*)l, 16, 0, 0);
}

// ---------------- fp32 -> fp16 hi/lo split (vectorized) ----------------
__global__ void cvt_split(const float* __restrict__ in, f16* __restrict__ hi,
                          f16* __restrict__ lo, long n) {
  long i = ((long)blockIdx.x * blockDim.x + threadIdx.x) * 4;
  if (i >= n) return;
  const float4 v = *(const float4*)(in + i);
  f16x4 h, l;
  h.a = (f16)v.x; l.a = (f16)(v.x - (float)h.a);
  h.b = (f16)v.y; l.b = (f16)(v.y - (float)h.b);
  h.c = (f16)v.z; l.c = (f16)(v.z - (float)h.c);
  h.d = (f16)v.w; l.d = (f16)(v.w - (float)h.d);
  *(f16x4*)(hi + i) = h;
  *(f16x4*)(lo + i) = l;
}

// ---------------- bias_sum[e] = sum_r msg_b[r,e] ----------------
__global__ void bias_sum_k(const float* __restrict__ msg_b, float* __restrict__ bs) {
  int e = threadIdx.x;  // 512 threads
  float s = 0.f;
  for (int r = 0; r < 8; ++r) s += msg_b[r * 512 + e];
  bs[e] = s;
}

// ---------------- split-fp16 MFMA GEMM, B^T pattern ----------------
// C[m,n] = sum_{r,k} A_r[m,k] * B_r[n,k] (+bias[n]), K=512 per r, lda=ldb=512.
// A = Ah (+Al if SA), B = Bh (+Bl if SB); acc += Ah*Bh [+Ah*Bl] [+Al*Bh].
// 128x128 tile, 4 waves 2x2, each 64x64 via 4x4 MFMA 16x16x32_f16 tiles.
// Outputs: Chi/Clo fp16 split pair (if Chi) and/or Cf fp32 (if Cf).
template <int SA, int SB>
__global__ __launch_bounds__(256) void gemm_sp(
    const f16* __restrict__ Ah, const f16* __restrict__ Al,
    const f16* __restrict__ Bh, const f16* __restrict__ Bl,
    f16* __restrict__ Chi, f16* __restrict__ Clo, float* __restrict__ Cf,
    const float* __restrict__ bias, int N, int R, long sAr, long sBr,
    int zdiv, long sAzr, long sAzb, long sBzr, long sBzb, long sCz) {
  constexpr int TA = 1 + SA;
  constexpr int OFF_AL = 8192;            // f16 elements (128*64)
  constexpr int OFF_BH = 8192 * TA;
  constexpr int OFF_BL = OFF_BH + 8192;
  __shared__ __align__(16) f16 smem[(2 + SA + SB) * 8192];

  const int tid = threadIdx.x;
  const int z = blockIdx.z;
  const int zr = z % zdiv, zb = z / zdiv;
  const f16* Abh = Ah + (long)zr * sAzr + (long)zb * sAzb + (long)blockIdx.y * 128 * 512;
  const f16* Bbh = Bh + (long)zr * sBzr + (long)zb * sBzb + (long)blockIdx.x * 128 * 512;
  const f16* Abl = SA ? (Al + (Abh - Ah)) : nullptr;
  const f16* Bbl = SB ? (Bl + (Bbh - Bh)) : nullptr;
  const long cbase = (long)z * sCz;
  const int lane = tid & 63;
  const int w = tid >> 6;
  const int wm = (w & 1) << 6;
  const int wn = (w >> 1) << 6;

  f32x4 acc[4][4];
#pragma unroll
  for (int i = 0; i < 4; ++i)
#pragma unroll
    for (int j = 0; j < 4; ++j) acc[i][j] = (f32x4){0.f, 0.f, 0.f, 0.f};

  const int l15 = lane & 15;
  const int lk8 = (lane >> 4) * 8;

  for (int r = 0; r < R; ++r) {
    const long ro = (long)r * sAr;
    const long roB = (long)r * sBr;
    for (int k0 = 0; k0 < 512; k0 += 64) {
#pragma unroll
      for (int i = 0; i < 4; ++i) {
        const int c = i * 256 + tid;
        const long goff = (long)(c >> 3) * 512 + k0 + (c & 7) * 8;
        glds16(Abh + ro + goff, &smem[c * 8]);
        if constexpr (SA) glds16(Abl + ro + goff, &smem[OFF_AL + c * 8]);
        glds16(Bbh + roB + goff, &smem[OFF_BH + c * 8]);
        if constexpr (SB) glds16(Bbl + roB + goff, &smem[OFF_BL + c * 8]);
      }
      __syncthreads();
#pragma unroll
      for (int ks = 0; ks < 2; ++ks) {
        half8 ah[4], bh[4], al[4], bl[4];
#pragma unroll
        for (int t = 0; t < 4; ++t) {
          const int ro2 = (wm + t * 16 + l15) * 64 + ks * 32 + lk8;
          ah[t] = *(const half8*)&smem[ro2];
          if constexpr (SA) al[t] = *(const half8*)&smem[OFF_AL + ro2];
        }
#pragma unroll
        for (int t = 0; t < 4; ++t) {
          const int ro2 = (wn + t * 16 + l15) * 64 + ks * 32 + lk8;
          bh[t] = *(const half8*)&smem[OFF_BH + ro2];
          if constexpr (SB) bl[t] = *(const half8*)&smem[OFF_BL + ro2];
        }
#pragma unroll
        for (int mt = 0; mt < 4; ++mt)
#pragma unroll
          for (int nt = 0; nt < 4; ++nt) {
            acc[mt][nt] = __builtin_amdgcn_mfma_f32_16x16x32_f16(ah[mt], bh[nt], acc[mt][nt], 0, 0, 0);
            if constexpr (SB)
              acc[mt][nt] = __builtin_amdgcn_mfma_f32_16x16x32_f16(ah[mt], bl[nt], acc[mt][nt], 0, 0, 0);
            if constexpr (SA)
              acc[mt][nt] = __builtin_amdgcn_mfma_f32_16x16x32_f16(al[mt], bh[nt], acc[mt][nt], 0, 0, 0);
          }
      }
      __syncthreads();
    }
  }
  // epilogue: C/D layout col = lane&15, row = (lane>>4)*4 + v  [m89-verified]
  const int rb = (lane >> 4) << 2;
#pragma unroll
  for (int nt = 0; nt < 4; ++nt) {
    const int col = blockIdx.x * 128 + wn + nt * 16 + l15;
    const float bv = bias ? bias[col] : 0.f;
#pragma unroll
    for (int mt = 0; mt < 4; ++mt) {
      const long rowbase = (long)(blockIdx.y * 128 + wm + mt * 16 + rb) * N + col;
#pragma unroll
      for (int v = 0; v < 4; ++v) {
        const float cval = acc[mt][nt][v] + bv;
        const long idx = cbase + rowbase + (long)v * N;
        if (Chi) {
          const f16 h = (f16)cval;
          Chi[idx] = h;
          Clo[idx] = (f16)(cval - (float)h);
        }
        if (Cf) Cf[idx] = cval;
      }
    }
  }
}

// ---------------- GRU elementwise (fp32 gates) ----------------
__global__ void gru_k(const float* __restrict__ gi, const float* __restrict__ gh,
                      const float* __restrict__ hold, float* __restrict__ hnew,
                      f16* __restrict__ hhi, f16* __restrict__ hlo) {
  const int idx = blockIdx.x * blockDim.x + threadIdx.x;  // 4,194,304 threads
  const int row = idx >> 9, d = idx & 511;
  const long base = (long)row * 1536 + d;
  const float ir = gi[base],        hr = gh[base];
  const float iz = gi[base + 512],  hz = gh[base + 512];
  const float in_ = gi[base + 1024], hn = gh[base + 1024];
  const float h = hold[idx];
  const float r = 1.f / (1.f + __expf(-(ir + hr)));
  const float zg = 1.f / (1.f + __expf(-(iz + hz)));
  const float nt = tanhf(in_ + r * hn);
  const float o = (1.f - zg) * nt + zg * h;
  hnew[idx] = o;
  const f16 oh = (f16)o;
  hhi[idx] = oh;
  hlo[idx] = (f16)(o - (float)oh);
}

// ---------------- mean over nodes ----------------
__global__ void mean_k(const float* __restrict__ h, float* __restrict__ out) {
  const int b = blockIdx.x;   // 16
  const int d = threadIdx.x;  // 512
  const float* p = h + (long)b * 512 * 512 + d;
  float s = 0.f;
  for (int i = 0; i < 512; ++i) s += p[(long)i * 512];
  out[b * 512 + d] = s * (1.f / 512.f);
}

extern "C" void kernel_launch(void* const* d_in, const int* in_sizes, int n_in,
                              void* d_out, int out_size, void* d_ws, size_t ws_size,
                              hipStream_t stream) {
  const float* nodes = (const float*)d_in[0];  // [16,512,512]
  const float* edges = (const float*)d_in[1];  // [16,8,512,512]
  const float* msg_W = (const float*)d_in[2];  // [8,512,512]
  const float* msg_b = (const float*)d_in[3];  // [8,512]
  const float* w_ih  = (const float*)d_in[4];  // [1536,512]
  const float* w_hh  = (const float*)d_in[5];  // [1536,512]
  const float* b_ih  = (const float*)d_in[6];  // [1536]
  const float* b_hh  = (const float*)d_in[7];  // [1536]
  float* out = (float*)d_out;                  // [16,512]

  char* ws = (char*)d_ws;
  size_t off = 0;
  auto alloc = [&](size_t bytes) -> char* {
    char* p = ws + off;
    off += (bytes + 1023) & ~(size_t)1023;
    return p;
  };
  f16* edges_hi = (f16*)alloc(33554432ull * 2);
  f16* edges_lo = (f16*)alloc(33554432ull * 2);
  f16* W_hi     = (f16*)alloc(2097152ull * 2);
  f16* W_lo     = (f16*)alloc(2097152ull * 2);
  f16* wih_hi   = (f16*)alloc(786432ull * 2);
  f16* wih_lo   = (f16*)alloc(786432ull * 2);
  f16* whh_hi   = (f16*)alloc(786432ull * 2);
  f16* whh_lo   = (f16*)alloc(786432ull * 2);
  f16* h_hi     = (f16*)alloc(4194304ull * 2);
  f16* h_lo     = (f16*)alloc(4194304ull * 2);
  f16* hWT_hi   = (f16*)alloc(33554432ull * 2);  // reused as gi (fp32) after G2
  f16* hWT_lo   = (f16*)alloc(33554432ull * 2);  // reused as gh (fp32) after G2
  f16* agg_hi   = (f16*)alloc(4194304ull * 2);
  f16* agg_lo   = (f16*)alloc(4194304ull * 2);
  float* h0     = (float*)alloc(4194304ull * 4);
  float* bsum   = (float*)alloc(512 * 4);
  float* gi = (float*)hWT_hi;  // 8192*1536*4 = 50.3MB <= 67.1MB region
  float* gh = (float*)hWT_lo;
  // total ws use ~334 MB

  // one-time converts
  cvt_split<<<32768, 256, 0, stream>>>(edges, edges_hi, edges_lo, 33554432L);
  cvt_split<<<2048,  256, 0, stream>>>(msg_W, W_hi, W_lo, 2097152L);
  cvt_split<<<768,   256, 0, stream>>>(w_ih, wih_hi, wih_lo, 786432L);
  cvt_split<<<768,   256, 0, stream>>>(w_hh, whh_hi, whh_lo, 786432L);
  cvt_split<<<4096,  256, 0, stream>>>(nodes, h_hi, h_lo, 4194304L);
  bias_sum_k<<<1, 512, 0, stream>>>(msg_b, bsum);

  for (int step = 0; step < 2; ++step) {
    const float* hold = step ? (const float*)h0 : nodes;
    // G1: hWT[b*8+r][e,j] = sum_d W[r][e,d] * h[b][j,d]  (split x split)
    gemm_sp<1, 1><<<dim3(4, 4, 128), 256, 0, stream>>>(
        W_hi, W_lo, h_hi, h_lo, hWT_hi, hWT_lo, nullptr, nullptr,
        512, 1, 0L, 0L, 8, 262144L, 0L, 0L, 262144L, 262144L);
    // G2: agg[b][i,e] = sum_r sum_j E[b,r][i,j] * hWT[b*8+r][e,j] + bsum[e]
    gemm_sp<1, 1><<<dim3(4, 4, 16), 256, 0, stream>>>(
        edges_hi, edges_lo, hWT_hi, hWT_lo, agg_hi, agg_lo, nullptr, bsum,
        512, 8, 262144L, 262144L, 1, 0L, 2097152L, 0L, 2097152L, 262144L);
    // G3: gi[i,g] = sum_e agg[i,e] * w_ih[g,e] + b_ih[g]  (split-A, fp32 out)
    gemm_sp<1, 0><<<dim3(12, 64, 1), 256, 0, stream>>>(
        agg_hi, agg_lo, wih_hi, nullptr, nullptr, nullptr, gi, b_ih,
        1536, 1, 0L, 0L, 1, 0L, 0L, 0L, 0L, 0L);
    // G4: gh[i,g] = sum_d h[i,d] * w_hh[g,d] + b_hh[g]  (single, fp32 out)
    gemm_sp<0, 0><<<dim3(12, 64, 1), 256, 0, stream>>>(
        h_hi, nullptr, whh_hi, nullptr, nullptr, nullptr, gh, b_hh,
        1536, 1, 0L, 0L, 1, 0L, 0L, 0L, 0L, 0L);
    // GRU update -> h0 (fp32) + h hi/lo fp16 for next step
    gru_k<<<16384, 256, 0, stream>>>(gi, gh, hold, h0, h_hi, h_lo);
  }
  mean_k<<<16, 512, 0, stream>>>(h0, out);
}

// Round 3
// 1092.255 us; speedup vs baseline: 1.0344x; 1.0344x over previous
//
#include <hip/hip_runtime.h>

typedef _Float16 f16;
typedef __attribute__((ext_vector_type(8))) _Float16 half8;
typedef __attribute__((ext_vector_type(4))) float f32x4;

struct f16x4 { f16 a, b, c, d; };

__device__ __forceinline__ void glds16(const f16* g, f16* l) {
  __builtin_amdgcn_global_load_lds(
      (const __attribute__((address_space(1))) void*)g,
      (__attribute__((address_space(3))) void*)l, 16, 0, 0);
}

// ---------------- fp32 -> fp16 hi/lo split (vectorized) ----------------
__global__ void cvt_split(const float* __restrict__ in, f16* __restrict__ hi,
                          f16* __restrict__ lo, long n) {
  long i = ((long)blockIdx.x * blockDim.x + threadIdx.x) * 4;
  if (i >= n) return;
  const float4 v = *(const float4*)(in + i);
  f16x4 h, l;
  h.a = (f16)v.x; l.a = (f16)(v.x - (float)h.a);
  h.b = (f16)v.y; l.b = (f16)(v.y - (float)h.b);
  h.c = (f16)v.z; l.c = (f16)(v.z - (float)h.c);
  h.d = (f16)v.w; l.d = (f16)(v.w - (float)h.d);
  *(f16x4*)(hi + i) = h;
  *(f16x4*)(lo + i) = l;
}

// ---------------- bias_sum[e] = sum_r msg_b[r,e] ----------------
__global__ void bias_sum_k(const float* __restrict__ msg_b, float* __restrict__ bs) {
  int e = threadIdx.x;  // 512 threads
  float s = 0.f;
  for (int r = 0; r < 8; ++r) s += msg_b[r * 512 + e];
  bs[e] = s;
}

// ---------------- split-fp16 MFMA GEMM, B^T pattern, BK=32, swizzled ----------------
// C[m,n] = sum_{r,k} A_r[m,k] * B_r[n,k] (+bias[n]), K=512 per r, lda=ldb=512.
// acc += Ah*Bh [+Ah*Bl if SB] [+Al*Bh if SA].  128x128 tile, 4 waves 2x2.
// LDS: (2+SA+SB)*8KB; 16B chunks XOR-swizzled: slot = chunk ^ ((row>>1)&3)
// (read side: uniform 2-way bank aliasing = free).
// Output: Chi/Clo f16 split pair, or fp32 to (zr ? Cf1 : Cf0).
template <int SA, int SB>
__global__ __launch_bounds__(256) void gemm_sp(
    const f16* __restrict__ Ah, const f16* __restrict__ Al,
    const f16* __restrict__ Bh, const f16* __restrict__ Bl,
    f16* __restrict__ Chi, f16* __restrict__ Clo,
    float* __restrict__ Cf0, float* __restrict__ Cf1,
    const float* __restrict__ bias, int N, int R, long sAr, long sBr,
    int zdiv, long sAzr, long sAzb, long sBzr, long sBzb,
    long sCzr, long sCzb) {
  constexpr int OAL = 4096;              // f16 elems per 128x32 tile
  constexpr int OBH = (1 + SA) * 4096;
  constexpr int OBL = OBH + 4096;
  __shared__ __align__(16) f16 smem[(2 + SA + SB) * 4096];

  const int tid = threadIdx.x;
  const int z = blockIdx.z;
  const int zr = z % zdiv, zb = z / zdiv;
  const f16* Abh = Ah + (long)zr * sAzr + (long)zb * sAzb + (long)blockIdx.y * 128 * 512;
  const f16* Bbh = Bh + (long)zr * sBzr + (long)zb * sBzb + (long)blockIdx.x * 128 * 512;
  const f16* Abl = SA ? (Al + (Abh - Ah)) : nullptr;
  const f16* Bbl = SB ? (Bl + (Bbh - Bh)) : nullptr;
  const long cbase = (long)zr * sCzr + (long)zb * sCzb;
  const int lane = tid & 63;
  const int w = tid >> 6;
  const int wm = (w & 1) << 6;
  const int wn = (w >> 1) << 6;

  f32x4 acc[4][4];
#pragma unroll
  for (int i = 0; i < 4; ++i)
#pragma unroll
    for (int j = 0; j < 4; ++j) acc[i][j] = (f32x4){0.f, 0.f, 0.f, 0.f};

  const int l15 = lane & 15;
  // swizzled element offset within a row (wave-constant per lane):
  // frag chunk q = lane>>4, slot = q ^ ((row>>1)&3); wm/wn/t*16 don't affect key
  const int sw = (((lane >> 4) ^ ((l15 >> 1) & 3)) << 3);

  for (int r = 0; r < R; ++r) {
    const long ro = (long)r * sAr;
    const long roB = (long)r * sBr;
    for (int k0 = 0; k0 < 512; k0 += 32) {
#pragma unroll
      for (int i = 0; i < 2; ++i) {
        const int c = i * 256 + tid;                  // LDS slot index (16B units)
        const int kc = (c & 3) ^ ((c >> 3) & 3);      // swizzled global chunk
        const long goff = (long)(c >> 2) * 512 + k0 + kc * 8;
        glds16(Abh + ro + goff, &smem[c * 8]);
        if constexpr (SA) glds16(Abl + ro + goff, &smem[OAL + c * 8]);
        glds16(Bbh + roB + goff, &smem[OBH + c * 8]);
        if constexpr (SB) glds16(Bbl + roB + goff, &smem[OBL + c * 8]);
      }
      __syncthreads();
      half8 ah[4], al[4], bh[4], bl[4];
#pragma unroll
      for (int t = 0; t < 4; ++t) {
        const int ro2 = (wm + t * 16 + l15) * 32 + sw;
        ah[t] = *(const half8*)&smem[ro2];
        if constexpr (SA) al[t] = *(const half8*)&smem[OAL + ro2];
      }
#pragma unroll
      for (int t = 0; t < 4; ++t) {
        const int ro2 = (wn + t * 16 + l15) * 32 + sw;
        bh[t] = *(const half8*)&smem[OBH + ro2];
        if constexpr (SB) bl[t] = *(const half8*)&smem[OBL + ro2];
      }
#pragma unroll
      for (int mt = 0; mt < 4; ++mt)
#pragma unroll
        for (int nt = 0; nt < 4; ++nt) {
          acc[mt][nt] = __builtin_amdgcn_mfma_f32_16x16x32_f16(ah[mt], bh[nt], acc[mt][nt], 0, 0, 0);
          if constexpr (SB)
            acc[mt][nt] = __builtin_amdgcn_mfma_f32_16x16x32_f16(ah[mt], bl[nt], acc[mt][nt], 0, 0, 0);
          if constexpr (SA)
            acc[mt][nt] = __builtin_amdgcn_mfma_f32_16x16x32_f16(al[mt], bh[nt], acc[mt][nt], 0, 0, 0);
        }
      __syncthreads();
    }
  }
  // epilogue: C/D layout col = lane&15, row = (lane>>4)*4 + v  [m89-verified]
  float* __restrict__ Cf = (zr && Cf1) ? Cf1 : Cf0;
  const int rb = (lane >> 4) << 2;
#pragma unroll
  for (int nt = 0; nt < 4; ++nt) {
    const int col = blockIdx.x * 128 + wn + nt * 16 + l15;
    const float bv = bias ? bias[col] : 0.f;
#pragma unroll
    for (int mt = 0; mt < 4; ++mt) {
      const long rowbase = (long)(blockIdx.y * 128 + wm + mt * 16 + rb) * N + col;
#pragma unroll
      for (int v = 0; v < 4; ++v) {
        const float cval = acc[mt][nt][v] + bv;
        const long idx = cbase + rowbase + (long)v * N;
        if (Chi) {
          const f16 h = (f16)cval;
          Chi[idx] = h;
          Clo[idx] = (f16)(cval - (float)h);
        }
        if (Cf) Cf[idx] = cval;
      }
    }
  }
}

// ---------------- split-K reduce: agg = P + Q + bsum -> f16 hi/lo ----------------
__global__ void reduce_agg(const float* __restrict__ P, const float* __restrict__ Q,
                           const float* __restrict__ bsum,
                           f16* __restrict__ hi, f16* __restrict__ lo) {
  const long i = ((long)blockIdx.x * blockDim.x + threadIdx.x) * 4;  // 4096x256 blocks
  const float4 p = *(const float4*)(P + i);
  const float4 q = *(const float4*)(Q + i);
  const int col = (int)(i & 511);
  const float4 b = *(const float4*)(bsum + col);
  float v0 = p.x + q.x + b.x, v1 = p.y + q.y + b.y;
  float v2 = p.z + q.z + b.z, v3 = p.w + q.w + b.w;
  f16x4 h, l;
  h.a = (f16)v0; l.a = (f16)(v0 - (float)h.a);
  h.b = (f16)v1; l.b = (f16)(v1 - (float)h.b);
  h.c = (f16)v2; l.c = (f16)(v2 - (float)h.c);
  h.d = (f16)v3; l.d = (f16)(v3 - (float)h.d);
  *(f16x4*)(hi + i) = h;
  *(f16x4*)(lo + i) = l;
}

// ---------------- GRU elementwise (fp32 gates) ----------------
// hold: fp32 ptr (step 0) or combined from h hi/lo (step >= 1).
__global__ void gru_k(const float* __restrict__ gi, const float* __restrict__ gh,
                      const float* __restrict__ holdf,
                      f16* __restrict__ hhi, f16* __restrict__ hlo) {
  const int idx = blockIdx.x * blockDim.x + threadIdx.x;  // 4,194,304 threads
  const int row = idx >> 9, d = idx & 511;
  const long base = (long)row * 1536 + d;
  const float ir = gi[base],         hr = gh[base];
  const float iz = gi[base + 512],   hz = gh[base + 512];
  const float in_ = gi[base + 1024], hn = gh[base + 1024];
  const float h = holdf ? holdf[idx] : ((float)hhi[idx] + (float)hlo[idx]);
  const float r = 1.f / (1.f + __expf(-(ir + hr)));
  const float zg = 1.f / (1.f + __expf(-(iz + hz)));
  const float nt = tanhf(in_ + r * hn);
  const float o = (1.f - zg) * nt + zg * h;
  const f16 oh = (f16)o;
  hhi[idx] = oh;
  hlo[idx] = (f16)(o - (float)oh);
}

// ---------------- mean over nodes ----------------
__global__ void mean_k(const f16* __restrict__ hhi, const f16* __restrict__ hlo,
                       float* __restrict__ out) {
  const int b = blockIdx.x;   // 16
  const int d = threadIdx.x;  // 512
  const long base = (long)b * 512 * 512 + d;
  float s = 0.f;
  for (int i = 0; i < 512; ++i) {
    const long j = base + (long)i * 512;
    s += (float)hhi[j] + (float)hlo[j];
  }
  out[b * 512 + d] = s * (1.f / 512.f);
}

extern "C" void kernel_launch(void* const* d_in, const int* in_sizes, int n_in,
                              void* d_out, int out_size, void* d_ws, size_t ws_size,
                              hipStream_t stream) {
  const float* nodes = (const float*)d_in[0];  // [16,512,512]
  const float* edges = (const float*)d_in[1];  // [16,8,512,512]
  const float* msg_W = (const float*)d_in[2];  // [8,512,512]
  const float* msg_b = (const float*)d_in[3];  // [8,512]
  const float* w_ih  = (const float*)d_in[4];  // [1536,512]
  const float* w_hh  = (const float*)d_in[5];  // [1536,512]
  const float* b_ih  = (const float*)d_in[6];  // [1536]
  const float* b_hh  = (const float*)d_in[7];  // [1536]
  float* out = (float*)d_out;                  // [16,512]

  char* ws = (char*)d_ws;
  size_t off = 0;
  auto alloc = [&](size_t bytes) -> char* {
    char* p = ws + off;
    off += (bytes + 1023) & ~(size_t)1023;
    return p;
  };
  f16* edges_hi = (f16*)alloc(33554432ull * 2);
  f16* edges_lo = (f16*)alloc(33554432ull * 2);
  f16* W_hi     = (f16*)alloc(2097152ull * 2);
  f16* W_lo     = (f16*)alloc(2097152ull * 2);
  f16* wih_hi   = (f16*)alloc(786432ull * 2);
  f16* wih_lo   = (f16*)alloc(786432ull * 2);   // (unused this round, kept for layout stability)
  f16* whh_hi   = (f16*)alloc(786432ull * 2);
  f16* whh_lo   = (f16*)alloc(786432ull * 2);   // (unused)
  f16* h_hi     = (f16*)alloc(4194304ull * 2);
  f16* h_lo     = (f16*)alloc(4194304ull * 2);
  f16* hWT_hi   = (f16*)alloc(33554432ull * 2);  // head: gi fp32 after G3; tail: agg_hi/lo
  f16* hWT_lo   = (f16*)alloc(33554432ull * 2);  // head: gh fp32 after G4
  float* Pbuf   = (float*)alloc(4194304ull * 4); // split-K partial 0 (old agg slot)
  float* Qbuf   = (float*)alloc(4194304ull * 4); // split-K partial 1 (old h0 slot)
  float* bsum   = (float*)alloc(512 * 4);
  // carve the dead tail of hWT for agg (dead between G2-read and next G1-write):
  float* gi = (float*)hWT_hi;                 // 50.33 MB
  float* gh = (float*)hWT_lo;                 // 50.33 MB
  f16* agg_hi = hWT_hi + 25165824;            // 8.39 MB
  f16* agg_lo = agg_hi + 4194304;             // 8.39 MB (ends exactly at region end)
  // total ws use ~334 MB (identical to round-2 known-good footprint)

  // one-time converts
  cvt_split<<<32768, 256, 0, stream>>>(edges, edges_hi, edges_lo, 33554432L);
  cvt_split<<<2048,  256, 0, stream>>>(msg_W, W_hi, W_lo, 2097152L);
  cvt_split<<<768,   256, 0, stream>>>(w_ih, wih_hi, wih_lo, 786432L);
  cvt_split<<<768,   256, 0, stream>>>(w_hh, whh_hi, whh_lo, 786432L);
  cvt_split<<<4096,  256, 0, stream>>>(nodes, h_hi, h_lo, 4194304L);
  bias_sum_k<<<1, 512, 0, stream>>>(msg_b, bsum);

  for (int step = 0; step < 2; ++step) {
    // G1: hWT[b*8+r][e,j] = sum_d W[r][e,d] * h[b][j,d]  (split x split)
    //     z = b*8+r: zr=r, zb=b
    gemm_sp<1, 1><<<dim3(4, 4, 128), 256, 0, stream>>>(
        W_hi, W_lo, h_hi, h_lo, hWT_hi, hWT_lo, nullptr, nullptr, nullptr,
        512, 1, 0L, 0L, 8, 262144L, 0L, 0L, 262144L, 262144L, 2097152L);
    // G2: split-K x2 over relation halves: z = b*2+rh (zr=rh, zb=b), R=4
    //     partial[rh][i,e] fp32 -> Pbuf/Qbuf
    gemm_sp<1, 1><<<dim3(4, 4, 32), 256, 0, stream>>>(
        edges_hi, edges_lo, hWT_hi, hWT_lo, nullptr, nullptr, Pbuf, Qbuf, nullptr,
        512, 4, 262144L, 262144L, 2, 1048576L, 2097152L, 1048576L, 2097152L,
        0L, 262144L);
    // reduce: agg = P + Q + bsum -> hi/lo (into hWT tail)
    reduce_agg<<<4096, 256, 0, stream>>>(Pbuf, Qbuf, bsum, agg_hi, agg_lo);
    // G3: gi[i,g] = sum_e agg[i,e] * w_ih[g,e] + b_ih[g]  (split-A, fp32 out)
    gemm_sp<1, 0><<<dim3(12, 64, 1), 256, 0, stream>>>(
        agg_hi, agg_lo, wih_hi, nullptr, nullptr, nullptr, gi, nullptr, b_ih,
        1536, 1, 0L, 0L, 1, 0L, 0L, 0L, 0L, 0L, 0L);
    // G4: gh[i,g] = sum_d h[i,d] * w_hh[g,d] + b_hh[g]  (single, fp32 out)
    gemm_sp<0, 0><<<dim3(12, 64, 1), 256, 0, stream>>>(
        h_hi, nullptr, whh_hi, nullptr, nullptr, nullptr, gh, nullptr, b_hh,
        1536, 1, 0L, 0L, 1, 0L, 0L, 0L, 0L, 0L, 0L);
    // GRU update -> h hi/lo (in-place safe: per-thread read-before-write)
    gru_k<<<16384, 256, 0, stream>>>(gi, gh, step ? nullptr : nodes, h_hi, h_lo);
  }
  mean_k<<<16, 512, 0, stream>>>(h_hi, h_lo, out);
}